// Round 4
// baseline (755.585 us; speedup 1.0000x reference)
//
#include <hip/hip_runtime.h>

#define N_NODES 50000
#define DIM 128
#define N_EDGES 800000
#define NEG_SLOPE 0.2f
#define LN_EPS 1e-5f

// Workspace layout (floats):
//   xr_acc : N*D   (x_r during alpha phase; then zeroed and reused as aggregation acc)
//   alpha  : E
//   seg_sum: N
//   seg_max: N (int, ordered-float encoding)
// total ~29.2 MB. x_l lives in d_out until gemm_out overwrites it.

__device__ __forceinline__ int f2ord(float f) {
    int i = __float_as_int(f);
    return i < 0 ? (i ^ 0x7FFFFFFF) : i;
}
__device__ __forceinline__ float ord2f(int i) {
    return __int_as_float(i < 0 ? (i ^ 0x7FFFFFFF) : i);
}

// K1: xl = x@W_l + b_l -> d_out ; xr = x@W_r + b_r -> ws. 8 nodes/block, 256 thr.
__global__ __launch_bounds__(256) void lin_kernel(
    const float* __restrict__ x,
    const float* __restrict__ Wl, const float* __restrict__ bl,
    const float* __restrict__ Wr, const float* __restrict__ br,
    float* __restrict__ xl, float* __restrict__ xr)
{
    __shared__ float xs[8][DIM];
    const int node0 = blockIdx.x * 8;
    const int t = threadIdx.x;
    for (int i = t; i < 8 * DIM; i += 256) {
        int n = node0 + (i >> 7);
        xs[i >> 7][i & 127] = (n < N_NODES) ? x[(size_t)n * DIM + (i & 127)] : 0.f;
    }
    __syncthreads();
    const int d = t & 127;
    const float* W = (t < 128) ? Wl : Wr;
    const float* b = (t < 128) ? bl : br;
    float*       o = (t < 128) ? xl : xr;
    float acc[8];
#pragma unroll
    for (int i = 0; i < 8; i++) acc[i] = b[d];
    for (int k = 0; k < DIM; k++) {
        float w = W[k * DIM + d];
#pragma unroll
        for (int i = 0; i < 8; i++) acc[i] += xs[i][k] * w;
    }
#pragma unroll
    for (int i = 0; i < 8; i++) {
        int n = node0 + i;
        if (n < N_NODES) o[(size_t)n * DIM + d] = acc[i];
    }
}

__global__ void init_kernel(int* __restrict__ seg_max_i, float* __restrict__ seg_sum) {
    int i = blockIdx.x * 256 + threadIdx.x;
    if (i < N_NODES) {
        seg_max_i[i] = (int)0x80000000;  // ordered-int -inf
        seg_sum[i] = 0.f;
    }
}

// K2: per-edge logit + atomic segment max. One wave (64 lanes) per edge, 2 dims/lane.
__global__ __launch_bounds__(256) void alpha_kernel(
    const float* __restrict__ xl, const float* __restrict__ xr,
    const int* __restrict__ src_idx, const int* __restrict__ dst_idx,
    const float* __restrict__ ea, const float* __restrict__ We,
    const float* __restrict__ att,
    float* __restrict__ alpha, int* __restrict__ seg_max_i)
{
    const int wid = blockIdx.x * 4 + (threadIdx.x >> 6);
    const int lane = threadIdx.x & 63;
    if (wid >= N_EDGES) return;
    const int e = wid;
    const int s = src_idx[e];
    const int dv = dst_idx[e];
    const float a0 = ea[(size_t)e * 3 + 0];
    const float a1 = ea[(size_t)e * 3 + 1];
    const float a2 = ea[(size_t)e * 3 + 2];
    const size_t sb = (size_t)s * DIM, db = (size_t)dv * DIM;
    float m0 = xl[sb + lane] + xr[db + lane]
             + a0 * We[lane] + a1 * We[DIM + lane] + a2 * We[2 * DIM + lane];
    float m1 = xl[sb + 64 + lane] + xr[db + 64 + lane]
             + a0 * We[64 + lane] + a1 * We[DIM + 64 + lane] + a2 * We[2 * DIM + 64 + lane];
    m0 = m0 > 0.f ? m0 : NEG_SLOPE * m0;
    m1 = m1 > 0.f ? m1 : NEG_SLOPE * m1;
    float p = m0 * att[lane] + m1 * att[64 + lane];
#pragma unroll
    for (int o = 32; o > 0; o >>= 1) p += __shfl_xor(p, o, 64);
    if (lane == 0) {
        alpha[e] = p;
        atomicMax(&seg_max_i[dv], f2ord(p));
    }
}

// K3: ex = exp(alpha - segmax[dst]); seg_sum += ex. One thread per edge.
__global__ __launch_bounds__(256) void exp_kernel(
    const int* __restrict__ dst_idx, const int* __restrict__ seg_max_i,
    float* __restrict__ alpha, float* __restrict__ seg_sum)
{
    int e = blockIdx.x * 256 + threadIdx.x;
    if (e >= N_EDGES) return;
    int dv = dst_idx[e];
    float ex = expf(alpha[e] - ord2f(seg_max_i[dv]));
    alpha[e] = ex;
    atomicAdd(&seg_sum[dv], ex);
}

// K4: acc[dst] += x[src] * (ex / (seg_sum[dst]+1e-16)).  (raw x, not x_l!)
__global__ __launch_bounds__(256) void agg_raw_kernel(
    const float* __restrict__ x,
    const int* __restrict__ src_idx, const int* __restrict__ dst_idx,
    const float* __restrict__ alpha, const float* __restrict__ seg_sum,
    float* __restrict__ acc)
{
    const int wid = blockIdx.x * 4 + (threadIdx.x >> 6);
    const int lane = threadIdx.x & 63;
    if (wid >= N_EDGES) return;
    const int e = wid;
    const int s = src_idx[e];
    const int dv = dst_idx[e];
    const float w = alpha[e] / (seg_sum[dv] + 1e-16f);
    const size_t sb = (size_t)s * DIM, db = (size_t)dv * DIM;
    atomicAdd(&acc[db + lane], x[sb + lane] * w);
    atomicAdd(&acc[db + 64 + lane], x[sb + 64 + lane] * w);
}

// K5: out = acc @ W_l + b_l   (valid since sum of softmax weights == 1, b_l==0
// for isolated nodes). Overwrites d_out (x_l is dead after alpha_kernel).
__global__ __launch_bounds__(256) void gemm_out_kernel(
    const float* __restrict__ acc,
    const float* __restrict__ Wl, const float* __restrict__ bl,
    float* __restrict__ out)
{
    __shared__ float xs[8][DIM];
    const int node0 = blockIdx.x * 8;
    const int t = threadIdx.x;
    for (int i = t; i < 8 * DIM; i += 256) {
        int n = node0 + (i >> 7);
        xs[i >> 7][i & 127] = (n < N_NODES) ? acc[(size_t)n * DIM + (i & 127)] : 0.f;
    }
    __syncthreads();
    const int d = t & 127;
    const int g = (t >> 7) * 4;  // node sub-group 0..3 or 4..7
    float a[4];
#pragma unroll
    for (int i = 0; i < 4; i++) a[i] = bl[d];
    for (int k = 0; k < DIM; k++) {
        float w = Wl[k * DIM + d];
#pragma unroll
        for (int i = 0; i < 4; i++) a[i] += xs[g + i][k] * w;
    }
#pragma unroll
    for (int i = 0; i < 4; i++) {
        int n = node0 + g + i;
        if (n < N_NODES) out[(size_t)n * DIM + d] = a[i];
    }
}

// K6: out = LN(x + rw*(out + bias)) * gamma + beta, in-place. One wave per node.
__global__ __launch_bounds__(256) void ln_kernel(
    const float* __restrict__ x, const float* __restrict__ bias,
    const float* __restrict__ rw_p,
    const float* __restrict__ gamma, const float* __restrict__ beta,
    float* __restrict__ out)
{
    const int wid = blockIdx.x * 4 + (threadIdx.x >> 6);
    const int lane = threadIdx.x & 63;
    if (wid >= N_NODES) return;
    const float rw = rw_p[0];
    const size_t nb = (size_t)wid * DIM;
    float a0 = out[nb + lane], a1 = out[nb + 64 + lane];
    float v0 = x[nb + lane] + rw * (a0 + bias[lane]);
    float v1 = x[nb + 64 + lane] + rw * (a1 + bias[64 + lane]);
    float s = v0 + v1;
#pragma unroll
    for (int o = 32; o > 0; o >>= 1) s += __shfl_xor(s, o, 64);
    const float mu = s * (1.f / DIM);
    float d0 = v0 - mu, d1 = v1 - mu;
    float q = d0 * d0 + d1 * d1;
#pragma unroll
    for (int o = 32; o > 0; o >>= 1) q += __shfl_xor(q, o, 64);
    const float rstd = rsqrtf(q * (1.f / DIM) + LN_EPS);
    out[nb + lane]      = d0 * rstd * gamma[lane]      + beta[lane];
    out[nb + 64 + lane] = d1 * rstd * gamma[64 + lane] + beta[64 + lane];
}

extern "C" void kernel_launch(void* const* d_in, const int* in_sizes, int n_in,
                              void* d_out, int out_size, void* d_ws, size_t ws_size,
                              hipStream_t stream)
{
    const float* x    = (const float*)d_in[0];
    const int*   ei   = (const int*)d_in[1];
    const float* ea   = (const float*)d_in[2];
    const float* Wl   = (const float*)d_in[3];
    const float* bl   = (const float*)d_in[4];
    const float* Wr   = (const float*)d_in[5];
    const float* br   = (const float*)d_in[6];
    const float* We   = (const float*)d_in[7];
    const float* att  = (const float*)d_in[8];
    const float* bias = (const float*)d_in[9];
    const float* rw   = (const float*)d_in[10];
    const float* gmm  = (const float*)d_in[11];
    const float* bta  = (const float*)d_in[12];
    float* out = (float*)d_out;

    float* xr_acc  = (float*)d_ws;                        // N*D (x_r, then agg acc)
    float* alpha   = xr_acc + (size_t)N_NODES * DIM;      // E
    float* seg_sum = alpha + N_EDGES;                     // N
    int*   seg_max = (int*)(seg_sum + N_NODES);           // N

    const int* src_idx = ei;            // edge_index[0]
    const int* dst_idx = ei + N_EDGES;  // edge_index[1]

    float* xl = out;  // x_l lives in d_out through the alpha phase

    lin_kernel<<<(N_NODES + 7) / 8, 256, 0, stream>>>(x, Wl, bl, Wr, br, xl, xr_acc);
    init_kernel<<<(N_NODES + 255) / 256, 256, 0, stream>>>(seg_max, seg_sum);
    alpha_kernel<<<(N_EDGES + 3) / 4, 256, 0, stream>>>(xl, xr_acc, src_idx, dst_idx,
                                                        ea, We, att, alpha, seg_max);
    exp_kernel<<<(N_EDGES + 255) / 256, 256, 0, stream>>>(dst_idx, seg_max, alpha, seg_sum);
    // x_r is dead; reuse its slot as the aggregation accumulator.
    hipMemsetAsync(xr_acc, 0, (size_t)N_NODES * DIM * sizeof(float), stream);
    agg_raw_kernel<<<(N_EDGES + 3) / 4, 256, 0, stream>>>(x, src_idx, dst_idx,
                                                          alpha, seg_sum, xr_acc);
    gemm_out_kernel<<<(N_NODES + 7) / 8, 256, 0, stream>>>(xr_acc, Wl, bl, out);
    ln_kernel<<<(N_NODES + 3) / 4, 256, 0, stream>>>(x, bias, rw, gmm, bta, out);
}

// Round 5
// 528.181 us; speedup vs baseline: 1.4305x; 1.4305x over previous
//
#include <hip/hip_runtime.h>

#define N_NODES 50000
#define DIM 128
#define N_EDGES 800000
#define NEG_SLOPE 0.2f
#define LN_EPS 1e-5f
#define SCAN_BS 256
#define NB_SCAN ((N_NODES + SCAN_BS - 1) / SCAN_BS)   // 196

// ---------------- shared small helpers ----------------
__device__ __forceinline__ int f2ord(float f) {
    int i = __float_as_int(f);
    return i < 0 ? (i ^ 0x7FFFFFFF) : i;
}
__device__ __forceinline__ float ord2f(int i) {
    return __int_as_float(i < 0 ? (i ^ 0x7FFFFFFF) : i);
}

// K1: xl = x@W_l + b_l -> d_out ; xr = x@W_r + b_r -> ws. 8 nodes/block, 256 thr.
__global__ __launch_bounds__(256) void lin_kernel(
    const float* __restrict__ x,
    const float* __restrict__ Wl, const float* __restrict__ bl,
    const float* __restrict__ Wr, const float* __restrict__ br,
    float* __restrict__ xl, float* __restrict__ xr)
{
    __shared__ float xs[8][DIM];
    const int node0 = blockIdx.x * 8;
    const int t = threadIdx.x;
    for (int i = t; i < 8 * DIM; i += 256) {
        int n = node0 + (i >> 7);
        xs[i >> 7][i & 127] = (n < N_NODES) ? x[(size_t)n * DIM + (i & 127)] : 0.f;
    }
    __syncthreads();
    const int d = t & 127;
    const float* W = (t < 128) ? Wl : Wr;
    const float* b = (t < 128) ? bl : br;
    float*       o = (t < 128) ? xl : xr;
    float acc[8];
#pragma unroll
    for (int i = 0; i < 8; i++) acc[i] = b[d];
    for (int k = 0; k < DIM; k++) {
        float w = W[k * DIM + d];
#pragma unroll
        for (int i = 0; i < 8; i++) acc[i] += xs[i][k] * w;
    }
#pragma unroll
    for (int i = 0; i < 8; i++) {
        int n = node0 + i;
        if (n < N_NODES) o[(size_t)n * DIM + d] = acc[i];
    }
}

// ---------------- CSR build ----------------
__global__ __launch_bounds__(256) void hist_kernel(const int* __restrict__ dst_idx,
                                                   int* __restrict__ cnt) {
    int e = blockIdx.x * 256 + threadIdx.x;
    if (e < N_EDGES) atomicAdd(&cnt[dst_idx[e]], 1);
}

__global__ __launch_bounds__(SCAN_BS) void scan1_kernel(int* __restrict__ cnt,
                                                        int* __restrict__ partials) {
    __shared__ int sh[SCAN_BS];
    const int i = blockIdx.x * SCAN_BS + threadIdx.x;
    const int v = (i < N_NODES) ? cnt[i] : 0;
    sh[threadIdx.x] = v;
    __syncthreads();
    for (int off = 1; off < SCAN_BS; off <<= 1) {
        int t = (threadIdx.x >= off) ? sh[threadIdx.x - off] : 0;
        __syncthreads();
        sh[threadIdx.x] += t;
        __syncthreads();
    }
    if (i < N_NODES) cnt[i] = sh[threadIdx.x] - v;           // exclusive
    if (threadIdx.x == SCAN_BS - 1) partials[blockIdx.x] = sh[threadIdx.x];
}

__global__ __launch_bounds__(SCAN_BS) void scan2_kernel(int* __restrict__ partials) {
    __shared__ int sh[SCAN_BS];
    const int t = threadIdx.x;
    const int v = (t < NB_SCAN) ? partials[t] : 0;
    sh[t] = v;
    __syncthreads();
    for (int off = 1; off < SCAN_BS; off <<= 1) {
        int u = (t >= off) ? sh[t - off] : 0;
        __syncthreads();
        sh[t] += u;
        __syncthreads();
    }
    if (t < NB_SCAN) partials[t] = sh[t] - v;                // exclusive
}

__global__ __launch_bounds__(SCAN_BS) void scan3_kernel(int* __restrict__ cnt,
                                                        const int* __restrict__ partials) {
    const int i = blockIdx.x * SCAN_BS + threadIdx.x;
    if (i < N_NODES) cnt[i] += partials[blockIdx.x];
}

// scatter: cnt currently holds row_start; after this it holds row_end (cursor trick).
__global__ __launch_bounds__(256) void scatter_kernel(
    const int* __restrict__ src_idx, const int* __restrict__ dst_idx,
    int* __restrict__ cursor,
    int* __restrict__ sorted_src, int* __restrict__ sorted_eid) {
    int e = blockIdx.x * 256 + threadIdx.x;
    if (e >= N_EDGES) return;
    int pos = atomicAdd(&cursor[dst_idx[e]], 1);
    sorted_src[pos] = src_idx[e];
    sorted_eid[pos] = e;
}

// ---------------- CSR per-node phases ----------------
// K_A: one wave per node. logits + max + exp-sum. No atomics.
// After scatter: begin(v) = (v==0) ? 0 : cursor[v-1]; end(v) = cursor[v].
__global__ __launch_bounds__(256) void csr_alpha_kernel(
    const float* __restrict__ xl, const float* __restrict__ xr,
    const int* __restrict__ cursor,
    const int* __restrict__ sorted_src, const int* __restrict__ sorted_eid,
    const float* __restrict__ ea, const float* __restrict__ We,
    const float* __restrict__ att,
    float* __restrict__ alpha_s, float* __restrict__ seg_inv)
{
    const int v = blockIdx.x * 4 + (threadIdx.x >> 6);
    const int lane = threadIdx.x & 63;
    if (v >= N_NODES) return;
    const int begin = (v == 0) ? 0 : cursor[v - 1];
    const int end = cursor[v];
    const float2 xrv = *(const float2*)&xr[(size_t)v * DIM + 2 * lane];
    const float2 at  = *(const float2*)&att[2 * lane];
    const float2 we0 = *(const float2*)&We[0 * DIM + 2 * lane];
    const float2 we1 = *(const float2*)&We[1 * DIM + 2 * lane];
    const float2 we2 = *(const float2*)&We[2 * DIM + 2 * lane];
    float m = -3.4e38f;
    for (int pos = begin; pos < end; ++pos) {
        const int s = sorted_src[pos];
        const int e = sorted_eid[pos];
        const float a0 = ea[(size_t)e * 3 + 0];
        const float a1 = ea[(size_t)e * 3 + 1];
        const float a2 = ea[(size_t)e * 3 + 2];
        const float2 xls = *(const float2*)&xl[(size_t)s * DIM + 2 * lane];
        float t0 = xls.x + xrv.x + a0 * we0.x + a1 * we1.x + a2 * we2.x;
        float t1 = xls.y + xrv.y + a0 * we0.y + a1 * we1.y + a2 * we2.y;
        t0 = t0 > 0.f ? t0 : NEG_SLOPE * t0;
        t1 = t1 > 0.f ? t1 : NEG_SLOPE * t1;
        float p = t0 * at.x + t1 * at.y;
#pragma unroll
        for (int o = 32; o > 0; o >>= 1) p += __shfl_xor(p, o, 64);
        if (lane == 0) alpha_s[pos] = p;
        m = fmaxf(m, p);
    }
    __threadfence_block();   // make lane0's logit stores visible to all lanes' loads
    float ssum = 0.f;
    for (int pos = begin + lane; pos < end; pos += 64) {
        float ex = expf(alpha_s[pos] - m);
        alpha_s[pos] = ex;       // overwrite with unnormalized weight
        ssum += ex;
    }
#pragma unroll
    for (int o = 32; o > 0; o >>= 1) ssum += __shfl_xor(ssum, o, 64);
    if (lane == 0) seg_inv[v] = 1.f / (ssum + 1e-16f);
}

// K_B: one wave per node: acc[v] = (sum_e ex_e * x[src_e]) * inv. One write per node.
__global__ __launch_bounds__(256) void csr_agg_kernel(
    const float* __restrict__ x,
    const int* __restrict__ cursor, const int* __restrict__ sorted_src,
    const float* __restrict__ alpha_s, const float* __restrict__ seg_inv,
    float* __restrict__ acc)
{
    const int v = blockIdx.x * 4 + (threadIdx.x >> 6);
    const int lane = threadIdx.x & 63;
    if (v >= N_NODES) return;
    const int begin = (v == 0) ? 0 : cursor[v - 1];
    const int end = cursor[v];
    float a0 = 0.f, a1 = 0.f;
    for (int pos = begin; pos < end; ++pos) {
        const int s = sorted_src[pos];
        const float w = alpha_s[pos];
        const float2 xs = *(const float2*)&x[(size_t)s * DIM + 2 * lane];
        a0 += w * xs.x;
        a1 += w * xs.y;
    }
    const float inv = seg_inv[v];
    float2 r; r.x = a0 * inv; r.y = a1 * inv;
    *(float2*)&acc[(size_t)v * DIM + 2 * lane] = r;
}

// ---------------- fallback (round-4 proven) per-edge atomic phases ----------------
__global__ void init_kernel(int* __restrict__ seg_max_i, float* __restrict__ seg_sum) {
    int i = blockIdx.x * 256 + threadIdx.x;
    if (i < N_NODES) {
        seg_max_i[i] = (int)0x80000000;
        seg_sum[i] = 0.f;
    }
}

__global__ __launch_bounds__(256) void alpha_kernel(
    const float* __restrict__ xl, const float* __restrict__ xr,
    const int* __restrict__ src_idx, const int* __restrict__ dst_idx,
    const float* __restrict__ ea, const float* __restrict__ We,
    const float* __restrict__ att,
    float* __restrict__ alpha, int* __restrict__ seg_max_i)
{
    const int wid = blockIdx.x * 4 + (threadIdx.x >> 6);
    const int lane = threadIdx.x & 63;
    if (wid >= N_EDGES) return;
    const int e = wid;
    const int s = src_idx[e];
    const int dv = dst_idx[e];
    const float a0 = ea[(size_t)e * 3 + 0];
    const float a1 = ea[(size_t)e * 3 + 1];
    const float a2 = ea[(size_t)e * 3 + 2];
    const size_t sb = (size_t)s * DIM, db = (size_t)dv * DIM;
    float m0 = xl[sb + lane] + xr[db + lane]
             + a0 * We[lane] + a1 * We[DIM + lane] + a2 * We[2 * DIM + lane];
    float m1 = xl[sb + 64 + lane] + xr[db + 64 + lane]
             + a0 * We[64 + lane] + a1 * We[DIM + 64 + lane] + a2 * We[2 * DIM + 64 + lane];
    m0 = m0 > 0.f ? m0 : NEG_SLOPE * m0;
    m1 = m1 > 0.f ? m1 : NEG_SLOPE * m1;
    float p = m0 * att[lane] + m1 * att[64 + lane];
#pragma unroll
    for (int o = 32; o > 0; o >>= 1) p += __shfl_xor(p, o, 64);
    if (lane == 0) {
        alpha[e] = p;
        atomicMax(&seg_max_i[dv], f2ord(p));
    }
}

__global__ __launch_bounds__(256) void exp_kernel(
    const int* __restrict__ dst_idx, const int* __restrict__ seg_max_i,
    float* __restrict__ alpha, float* __restrict__ seg_sum)
{
    int e = blockIdx.x * 256 + threadIdx.x;
    if (e >= N_EDGES) return;
    int dv = dst_idx[e];
    float ex = expf(alpha[e] - ord2f(seg_max_i[dv]));
    alpha[e] = ex;
    atomicAdd(&seg_sum[dv], ex);
}

__global__ __launch_bounds__(256) void agg_raw_kernel(
    const float* __restrict__ x,
    const int* __restrict__ src_idx, const int* __restrict__ dst_idx,
    const float* __restrict__ alpha, const float* __restrict__ seg_sum,
    float* __restrict__ acc)
{
    const int wid = blockIdx.x * 4 + (threadIdx.x >> 6);
    const int lane = threadIdx.x & 63;
    if (wid >= N_EDGES) return;
    const int e = wid;
    const int s = src_idx[e];
    const int dv = dst_idx[e];
    const float w = alpha[e] / (seg_sum[dv] + 1e-16f);
    const size_t sb = (size_t)s * DIM, db = (size_t)dv * DIM;
    atomicAdd(&acc[db + lane], x[sb + lane] * w);
    atomicAdd(&acc[db + 64 + lane], x[sb + 64 + lane] * w);
}

// ---------------- epilogue ----------------
// out = acc @ W_l + b_l  (softmax weights sum to 1; b_l == 0 so deg-0 exact)
__global__ __launch_bounds__(256) void gemm_out_kernel(
    const float* __restrict__ acc,
    const float* __restrict__ Wl, const float* __restrict__ bl,
    float* __restrict__ out)
{
    __shared__ float xs[8][DIM];
    const int node0 = blockIdx.x * 8;
    const int t = threadIdx.x;
    for (int i = t; i < 8 * DIM; i += 256) {
        int n = node0 + (i >> 7);
        xs[i >> 7][i & 127] = (n < N_NODES) ? acc[(size_t)n * DIM + (i & 127)] : 0.f;
    }
    __syncthreads();
    const int d = t & 127;
    const int g = (t >> 7) * 4;
    float a[4];
#pragma unroll
    for (int i = 0; i < 4; i++) a[i] = bl[d];
    for (int k = 0; k < DIM; k++) {
        float w = Wl[k * DIM + d];
#pragma unroll
        for (int i = 0; i < 4; i++) a[i] += xs[g + i][k] * w;
    }
#pragma unroll
    for (int i = 0; i < 4; i++) {
        int n = node0 + g + i;
        if (n < N_NODES) out[(size_t)n * DIM + d] = a[i];
    }
}

__global__ __launch_bounds__(256) void ln_kernel(
    const float* __restrict__ x, const float* __restrict__ bias,
    const float* __restrict__ rw_p,
    const float* __restrict__ gamma, const float* __restrict__ beta,
    float* __restrict__ out)
{
    const int wid = blockIdx.x * 4 + (threadIdx.x >> 6);
    const int lane = threadIdx.x & 63;
    if (wid >= N_NODES) return;
    const float rw = rw_p[0];
    const size_t nb = (size_t)wid * DIM;
    float a0 = out[nb + lane], a1 = out[nb + 64 + lane];
    float v0 = x[nb + lane] + rw * (a0 + bias[lane]);
    float v1 = x[nb + 64 + lane] + rw * (a1 + bias[64 + lane]);
    float s = v0 + v1;
#pragma unroll
    for (int o = 32; o > 0; o >>= 1) s += __shfl_xor(s, o, 64);
    const float mu = s * (1.f / DIM);
    float d0 = v0 - mu, d1 = v1 - mu;
    float q = d0 * d0 + d1 * d1;
#pragma unroll
    for (int o = 32; o > 0; o >>= 1) q += __shfl_xor(q, o, 64);
    const float rstd = rsqrtf(q * (1.f / DIM) + LN_EPS);
    out[nb + lane]      = d0 * rstd * gamma[lane]      + beta[lane];
    out[nb + 64 + lane] = d1 * rstd * gamma[64 + lane] + beta[64 + lane];
}

extern "C" void kernel_launch(void* const* d_in, const int* in_sizes, int n_in,
                              void* d_out, int out_size, void* d_ws, size_t ws_size,
                              hipStream_t stream)
{
    const float* x    = (const float*)d_in[0];
    const int*   ei   = (const int*)d_in[1];
    const float* ea   = (const float*)d_in[2];
    const float* Wl   = (const float*)d_in[3];
    const float* bl   = (const float*)d_in[4];
    const float* Wr   = (const float*)d_in[5];
    const float* br   = (const float*)d_in[6];
    const float* We   = (const float*)d_in[7];
    const float* att  = (const float*)d_in[8];
    const float* bias = (const float*)d_in[9];
    const float* rw   = (const float*)d_in[10];
    const float* gmm  = (const float*)d_in[11];
    const float* bta  = (const float*)d_in[12];
    float* out = (float*)d_out;

    const int* src_idx = ei;            // edge_index[0]
    const int* dst_idx = ei + N_EDGES;  // edge_index[1]
    float* xl = out;                    // x_l lives in d_out through the alpha phase

    // CSR-path workspace layout
    float* buf        = (float*)d_ws;                      // N*D: x_r, then acc
    float* alpha_s    = buf + (size_t)N_NODES * DIM;       // E
    int*   sorted_src = (int*)(alpha_s + N_EDGES);         // E
    int*   sorted_eid = sorted_src + N_EDGES;              // E
    int*   cursor     = sorted_eid + N_EDGES;              // N (+pad)
    int*   partials   = cursor + N_NODES + 64;             // 256
    float* seg_inv    = (float*)(partials + 256);          // N
    const size_t need_csr = ((size_t)((char*)(seg_inv + N_NODES) - (char*)d_ws));

    if (ws_size >= need_csr) {
        // ---- CSR path ----
        hipMemsetAsync(cursor, 0, (size_t)(N_NODES + 64) * sizeof(int), stream);
        hist_kernel<<<(N_EDGES + 255) / 256, 256, 0, stream>>>(dst_idx, cursor);
        scan1_kernel<<<NB_SCAN, SCAN_BS, 0, stream>>>(cursor, partials);
        scan2_kernel<<<1, SCAN_BS, 0, stream>>>(partials);
        scan3_kernel<<<NB_SCAN, SCAN_BS, 0, stream>>>(cursor, partials);
        scatter_kernel<<<(N_EDGES + 255) / 256, 256, 0, stream>>>(src_idx, dst_idx,
                                                                  cursor, sorted_src, sorted_eid);
        lin_kernel<<<(N_NODES + 7) / 8, 256, 0, stream>>>(x, Wl, bl, Wr, br, xl, buf);
        csr_alpha_kernel<<<(N_NODES + 3) / 4, 256, 0, stream>>>(xl, buf, cursor,
                                                                sorted_src, sorted_eid,
                                                                ea, We, att, alpha_s, seg_inv);
        csr_agg_kernel<<<(N_NODES + 3) / 4, 256, 0, stream>>>(x, cursor, sorted_src,
                                                              alpha_s, seg_inv, buf);
        gemm_out_kernel<<<(N_NODES + 7) / 8, 256, 0, stream>>>(buf, Wl, bl, out);
        ln_kernel<<<(N_NODES + 3) / 4, 256, 0, stream>>>(x, bias, rw, gmm, bta, out);
    } else {
        // ---- fallback: round-4 proven atomic path (ws need ~29.2 MB) ----
        float* xr_acc  = (float*)d_ws;
        float* alpha   = xr_acc + (size_t)N_NODES * DIM;
        float* seg_sum = alpha + N_EDGES;
        int*   seg_max = (int*)(seg_sum + N_NODES);

        lin_kernel<<<(N_NODES + 7) / 8, 256, 0, stream>>>(x, Wl, bl, Wr, br, xl, xr_acc);
        init_kernel<<<(N_NODES + 255) / 256, 256, 0, stream>>>(seg_max, seg_sum);
        alpha_kernel<<<(N_EDGES + 3) / 4, 256, 0, stream>>>(xl, xr_acc, src_idx, dst_idx,
                                                            ea, We, att, alpha, seg_max);
        exp_kernel<<<(N_EDGES + 255) / 256, 256, 0, stream>>>(dst_idx, seg_max, alpha, seg_sum);
        hipMemsetAsync(xr_acc, 0, (size_t)N_NODES * DIM * sizeof(float), stream);
        agg_raw_kernel<<<(N_EDGES + 3) / 4, 256, 0, stream>>>(x, src_idx, dst_idx,
                                                              alpha, seg_sum, xr_acc);
        gemm_out_kernel<<<(N_NODES + 7) / 8, 256, 0, stream>>>(xr_acc, Wl, bl, out);
        ln_kernel<<<(N_NODES + 3) / 4, 256, 0, stream>>>(x, bias, rw, gmm, bta, out);
    }
}

// Round 6
// 389.935 us; speedup vs baseline: 1.9377x; 1.3545x over previous
//
#include <hip/hip_runtime.h>
#include <hip/hip_bf16.h>

#define N_NODES 50000
#define DIM 128
#define N_EDGES 800000
#define NEG_SLOPE 0.2f
#define LN_EPS 1e-5f
#define SCAN_BS 256
#define NB_SCAN ((N_NODES + SCAN_BS - 1) / SCAN_BS)   // 196

// Workspace layout:
//   xl_bf      : N*D bf16 (12.8 MB)  x@W_l+b_l, bf16
//   sorted_src : E int    (3.2 MB)
//   sorted_ea  : 3E f32   (9.6 MB)   edge_attr gathered into CSR order
//   cursor     : N+64 int (0.2 MB)   row_start -> row_end after scatter
//   partials   : 256 int
// total ~25.8 MB. x_r (f32) lives in d_out rows until the fused kernel
// overwrites each row with the final output (row-owned, no race).

// K1: xl = bf16(x@W_l + b_l) -> ws ; xr = x@W_r + b_r -> d_out. 8 nodes/block.
__global__ __launch_bounds__(256) void lin_kernel(
    const float* __restrict__ x,
    const float* __restrict__ Wl, const float* __restrict__ bl,
    const float* __restrict__ Wr, const float* __restrict__ br,
    __hip_bfloat16* __restrict__ xl_bf, float* __restrict__ xr)
{
    __shared__ float xs[8][DIM];
    const int node0 = blockIdx.x * 8;
    const int t = threadIdx.x;
    for (int i = t; i < 8 * DIM; i += 256) {
        int n = node0 + (i >> 7);
        xs[i >> 7][i & 127] = (n < N_NODES) ? x[(size_t)n * DIM + (i & 127)] : 0.f;
    }
    __syncthreads();
    const int d = t & 127;
    const bool is_l = (t < 128);
    const float* W = is_l ? Wl : Wr;
    const float* b = is_l ? bl : br;
    float acc[8];
#pragma unroll
    for (int i = 0; i < 8; i++) acc[i] = b[d];
    for (int k = 0; k < DIM; k++) {
        float w = W[k * DIM + d];
#pragma unroll
        for (int i = 0; i < 8; i++) acc[i] += xs[i][k] * w;
    }
#pragma unroll
    for (int i = 0; i < 8; i++) {
        int n = node0 + i;
        if (n < N_NODES) {
            if (is_l) xl_bf[(size_t)n * DIM + d] = __float2bfloat16(acc[i]);
            else      xr[(size_t)n * DIM + d] = acc[i];
        }
    }
}

// ---------------- CSR build ----------------
__global__ __launch_bounds__(256) void hist_kernel(const int* __restrict__ dst_idx,
                                                   int* __restrict__ cnt) {
    int e = blockIdx.x * 256 + threadIdx.x;
    if (e < N_EDGES) atomicAdd(&cnt[dst_idx[e]], 1);
}

__global__ __launch_bounds__(SCAN_BS) void scan1_kernel(int* __restrict__ cnt,
                                                        int* __restrict__ partials) {
    __shared__ int sh[SCAN_BS];
    const int i = blockIdx.x * SCAN_BS + threadIdx.x;
    const int v = (i < N_NODES) ? cnt[i] : 0;
    sh[threadIdx.x] = v;
    __syncthreads();
    for (int off = 1; off < SCAN_BS; off <<= 1) {
        int t = (threadIdx.x >= off) ? sh[threadIdx.x - off] : 0;
        __syncthreads();
        sh[threadIdx.x] += t;
        __syncthreads();
    }
    if (i < N_NODES) cnt[i] = sh[threadIdx.x] - v;           // exclusive
    if (threadIdx.x == SCAN_BS - 1) partials[blockIdx.x] = sh[threadIdx.x];
}

__global__ __launch_bounds__(SCAN_BS) void scan2_kernel(int* __restrict__ partials) {
    __shared__ int sh[SCAN_BS];
    const int t = threadIdx.x;
    const int v = (t < NB_SCAN) ? partials[t] : 0;
    sh[t] = v;
    __syncthreads();
    for (int off = 1; off < SCAN_BS; off <<= 1) {
        int u = (t >= off) ? sh[t - off] : 0;
        __syncthreads();
        sh[t] += u;
        __syncthreads();
    }
    if (t < NB_SCAN) partials[t] = sh[t] - v;                // exclusive
}

__global__ __launch_bounds__(SCAN_BS) void scan3_kernel(int* __restrict__ cnt,
                                                        const int* __restrict__ partials) {
    const int i = blockIdx.x * SCAN_BS + threadIdx.x;
    if (i < N_NODES) cnt[i] += partials[blockIdx.x];
}

// scatter edges into dst-sorted order; pre-gather edge_attr so the hot loop
// reads it sequentially. cursor becomes row_end.
__global__ __launch_bounds__(256) void scatter_kernel(
    const int* __restrict__ src_idx, const int* __restrict__ dst_idx,
    const float* __restrict__ ea,
    int* __restrict__ cursor,
    int* __restrict__ sorted_src, float* __restrict__ sorted_ea) {
    int e = blockIdx.x * 256 + threadIdx.x;
    if (e >= N_EDGES) return;
    int pos = atomicAdd(&cursor[dst_idx[e]], 1);
    sorted_src[pos] = src_idx[e];
    sorted_ea[3 * pos + 0] = ea[(size_t)e * 3 + 0];
    sorted_ea[3 * pos + 1] = ea[(size_t)e * 3 + 1];
    sorted_ea[3 * pos + 2] = ea[(size_t)e * 3 + 2];
}

// K_F: one wave per node. Single pass over the node's edges with online
// softmax (running m, s, rescaled accumulator), then fused residual+LN.
// out[] holds x_r on entry; each wave overwrites only its own row.
__global__ __launch_bounds__(256) void fused_node_kernel(
    const float* __restrict__ x, const __hip_bfloat16* __restrict__ xl_bf,
    const int* __restrict__ cursor,
    const int* __restrict__ sorted_src, const float* __restrict__ sorted_ea,
    const float* __restrict__ We, const float* __restrict__ att,
    const float* __restrict__ bias, const float* __restrict__ rw_p,
    const float* __restrict__ gamma, const float* __restrict__ beta,
    float* __restrict__ out)
{
    const int v = blockIdx.x * 4 + (threadIdx.x >> 6);
    const int lane = threadIdx.x & 63;
    if (v >= N_NODES) return;
    const int begin = (v == 0) ? 0 : cursor[v - 1];
    const int end = cursor[v];
    const size_t nb = (size_t)v * DIM + 2 * lane;
    const float2 xrv = *(const float2*)&out[nb];          // x_r row (parked in d_out)
    const float2 at  = *(const float2*)&att[2 * lane];
    const float2 we0 = *(const float2*)&We[0 * DIM + 2 * lane];
    const float2 we1 = *(const float2*)&We[1 * DIM + 2 * lane];
    const float2 we2 = *(const float2*)&We[2 * DIM + 2 * lane];

    float m = -3.4e38f, s = 0.f, a0 = 0.f, a1 = 0.f;
    for (int pos = begin; pos < end; ++pos) {
        const int sn = sorted_src[pos];
        const float ea0 = sorted_ea[3 * pos + 0];
        const float ea1 = sorted_ea[3 * pos + 1];
        const float ea2 = sorted_ea[3 * pos + 2];
        const unsigned xu = *(const unsigned*)&xl_bf[(size_t)sn * DIM + 2 * lane];
        const float xl0 = __uint_as_float(xu << 16);
        const float xl1 = __uint_as_float(xu & 0xffff0000u);
        float t0 = xl0 + xrv.x + ea0 * we0.x + ea1 * we1.x + ea2 * we2.x;
        float t1 = xl1 + xrv.y + ea0 * we0.y + ea1 * we1.y + ea2 * we2.y;
        t0 = t0 > 0.f ? t0 : NEG_SLOPE * t0;
        t1 = t1 > 0.f ? t1 : NEG_SLOPE * t1;
        float p = t0 * at.x + t1 * at.y;
#pragma unroll
        for (int o = 32; o > 0; o >>= 1) p += __shfl_xor(p, o, 64);
        const float mn = fmaxf(m, p);
        const float f = expf(m - mn);   // 0 on first edge (m=-inf)
        const float w = expf(p - mn);
        s  = s  * f + w;
        a0 = a0 * f + w * xl0;
        a1 = a1 * f + w * xl1;
        m = mn;
    }
    const float inv = 1.f / (s + 1e-16f);

    // epilogue: residual + LayerNorm
    const float2 xv = *(const float2*)&x[nb];
    const float rw = rw_p[0];
    float v0 = xv.x + rw * (a0 * inv + bias[2 * lane]);
    float v1 = xv.y + rw * (a1 * inv + bias[2 * lane + 1]);
    float sum = v0 + v1;
#pragma unroll
    for (int o = 32; o > 0; o >>= 1) sum += __shfl_xor(sum, o, 64);
    const float mu = sum * (1.f / DIM);
    const float d0 = v0 - mu, d1 = v1 - mu;
    float q = d0 * d0 + d1 * d1;
#pragma unroll
    for (int o = 32; o > 0; o >>= 1) q += __shfl_xor(q, o, 64);
    const float rstd = rsqrtf(q * (1.f / DIM) + LN_EPS);
    float2 r;
    r.x = d0 * rstd * gamma[2 * lane]     + beta[2 * lane];
    r.y = d1 * rstd * gamma[2 * lane + 1] + beta[2 * lane + 1];
    *(float2*)&out[nb] = r;
}

extern "C" void kernel_launch(void* const* d_in, const int* in_sizes, int n_in,
                              void* d_out, int out_size, void* d_ws, size_t ws_size,
                              hipStream_t stream)
{
    const float* x    = (const float*)d_in[0];
    const int*   ei   = (const int*)d_in[1];
    const float* ea   = (const float*)d_in[2];
    const float* Wl   = (const float*)d_in[3];
    const float* bl   = (const float*)d_in[4];
    const float* Wr   = (const float*)d_in[5];
    const float* br   = (const float*)d_in[6];
    const float* We   = (const float*)d_in[7];
    const float* att  = (const float*)d_in[8];
    const float* bias = (const float*)d_in[9];
    const float* rw   = (const float*)d_in[10];
    const float* gmm  = (const float*)d_in[11];
    const float* bta  = (const float*)d_in[12];
    float* out = (float*)d_out;

    const int* src_idx = ei;            // edge_index[0]
    const int* dst_idx = ei + N_EDGES;  // edge_index[1]

    __hip_bfloat16* xl_bf = (__hip_bfloat16*)d_ws;                 // N*D bf16
    int*   sorted_src = (int*)(xl_bf + (size_t)N_NODES * DIM);     // E
    float* sorted_ea  = (float*)(sorted_src + N_EDGES);            // 3E
    int*   cursor     = (int*)(sorted_ea + (size_t)3 * N_EDGES);   // N+64
    int*   partials   = cursor + N_NODES + 64;                     // 256

    hipMemsetAsync(cursor, 0, (size_t)(N_NODES + 64) * sizeof(int), stream);
    hist_kernel<<<(N_EDGES + 255) / 256, 256, 0, stream>>>(dst_idx, cursor);
    scan1_kernel<<<NB_SCAN, SCAN_BS, 0, stream>>>(cursor, partials);
    scan2_kernel<<<1, SCAN_BS, 0, stream>>>(partials);
    scan3_kernel<<<NB_SCAN, SCAN_BS, 0, stream>>>(cursor, partials);
    scatter_kernel<<<(N_EDGES + 255) / 256, 256, 0, stream>>>(src_idx, dst_idx, ea,
                                                              cursor, sorted_src, sorted_ea);
    lin_kernel<<<(N_NODES + 7) / 8, 256, 0, stream>>>(x, Wl, bl, Wr, br, xl_bf, out);
    fused_node_kernel<<<(N_NODES + 3) / 4, 256, 0, stream>>>(x, xl_bf, cursor,
                                                             sorted_src, sorted_ea,
                                                             We, att, bias, rw, gmm, bta, out);
}

// Round 7
// 348.659 us; speedup vs baseline: 2.1671x; 1.1184x over previous
//
#include <hip/hip_runtime.h>
#include <hip/hip_bf16.h>

#define N_NODES 50000
#define DIM 128
#define N_EDGES 800000
#define NEG_SLOPE 0.2f
#define LN_EPS 1e-5f
#define SCAN_BS 256
#define NB_SCAN ((N_NODES + SCAN_BS - 1) / SCAN_BS)   // 196
#define PADCAP (N_EDGES + 4 * N_NODES)                // >= sum(ceil4(deg)) = E + 3N

// Workspace layout:
//   xl_bf      : N*D bf16   (12.8 MB)
//   sorted_src : PADCAP int ( 4.0 MB)  dst-sorted, rows 4-aligned
//   sorted_ea  : 3*PADCAP   (12.0 MB)  edge_attr in CSR order
//   row_start  : N int                 padded exclusive scan (all %4==0)
//   cursor     : N int                 scatter cursor -> real row end
//   partials   : 256 int
// total ~29.2 MB. x_r (f32) parked in d_out rows until fused kernel overwrites.

// K1: xl = bf16(x@W_l + b_l) -> ws ; xr = x@W_r + b_r -> d_out. 8 nodes/block.
__global__ __launch_bounds__(256) void lin_kernel(
    const float* __restrict__ x,
    const float* __restrict__ Wl, const float* __restrict__ bl,
    const float* __restrict__ Wr, const float* __restrict__ br,
    __hip_bfloat16* __restrict__ xl_bf, float* __restrict__ xr)
{
    __shared__ float xs[8][DIM];
    const int node0 = blockIdx.x * 8;
    const int t = threadIdx.x;
    for (int i = t; i < 8 * DIM; i += 256) {
        int n = node0 + (i >> 7);
        xs[i >> 7][i & 127] = (n < N_NODES) ? x[(size_t)n * DIM + (i & 127)] : 0.f;
    }
    __syncthreads();
    const int d = t & 127;
    const bool is_l = (t < 128);
    const float* W = is_l ? Wl : Wr;
    const float* b = is_l ? bl : br;
    float acc[8];
#pragma unroll
    for (int i = 0; i < 8; i++) acc[i] = b[d];
    for (int k = 0; k < DIM; k++) {
        float w = W[k * DIM + d];
#pragma unroll
        for (int i = 0; i < 8; i++) acc[i] += xs[i][k] * w;
    }
#pragma unroll
    for (int i = 0; i < 8; i++) {
        int n = node0 + i;
        if (n < N_NODES) {
            if (is_l) xl_bf[(size_t)n * DIM + d] = __float2bfloat16(acc[i]);
            else      xr[(size_t)n * DIM + d] = acc[i];
        }
    }
}

// ---------------- CSR build (rows padded to %4 for aligned vector loads) ----
__global__ __launch_bounds__(256) void hist_kernel(const int* __restrict__ dst_idx,
                                                   int* __restrict__ cnt) {
    int e = blockIdx.x * 256 + threadIdx.x;
    if (e < N_EDGES) atomicAdd(&cnt[dst_idx[e]], 1);
}

__global__ __launch_bounds__(SCAN_BS) void scan1_kernel(int* __restrict__ cnt,
                                                        int* __restrict__ partials) {
    __shared__ int sh[SCAN_BS];
    const int i = blockIdx.x * SCAN_BS + threadIdx.x;
    const int deg = (i < N_NODES) ? cnt[i] : 0;
    const int v = (deg + 3) & ~3;                      // padded length
    sh[threadIdx.x] = v;
    __syncthreads();
    for (int off = 1; off < SCAN_BS; off <<= 1) {
        int u = (threadIdx.x >= off) ? sh[threadIdx.x - off] : 0;
        __syncthreads();
        sh[threadIdx.x] += u;
        __syncthreads();
    }
    if (i < N_NODES) cnt[i] = sh[threadIdx.x] - v;     // exclusive padded start
    if (threadIdx.x == SCAN_BS - 1) partials[blockIdx.x] = sh[threadIdx.x];
}

__global__ __launch_bounds__(SCAN_BS) void scan2_kernel(int* __restrict__ partials) {
    __shared__ int sh[SCAN_BS];
    const int t = threadIdx.x;
    const int v = (t < NB_SCAN) ? partials[t] : 0;
    sh[t] = v;
    __syncthreads();
    for (int off = 1; off < SCAN_BS; off <<= 1) {
        int u = (t >= off) ? sh[t - off] : 0;
        __syncthreads();
        sh[t] += u;
        __syncthreads();
    }
    if (t < NB_SCAN) partials[t] = sh[t] - v;
}

__global__ __launch_bounds__(SCAN_BS) void scan3_kernel(int* __restrict__ cnt,
                                                        const int* __restrict__ partials,
                                                        int* __restrict__ cursor) {
    const int i = blockIdx.x * SCAN_BS + threadIdx.x;
    if (i < N_NODES) {
        int rs = cnt[i] + partials[blockIdx.x];
        cnt[i] = rs;        // row_start (multiple of 4)
        cursor[i] = rs;     // scatter cursor; becomes real row end
    }
}

__global__ __launch_bounds__(256) void scatter_kernel(
    const int* __restrict__ src_idx, const int* __restrict__ dst_idx,
    const float* __restrict__ ea,
    int* __restrict__ cursor,
    int* __restrict__ sorted_src, float* __restrict__ sorted_ea) {
    int e = blockIdx.x * 256 + threadIdx.x;
    if (e >= N_EDGES) return;
    int pos = atomicAdd(&cursor[dst_idx[e]], 1);
    sorted_src[pos] = src_idx[e];
    sorted_ea[3 * pos + 0] = ea[(size_t)e * 3 + 0];
    sorted_ea[3 * pos + 1] = ea[(size_t)e * 3 + 1];
    sorted_ea[3 * pos + 2] = ea[(size_t)e * 3 + 2];
}

// K_F: one wave per node; 4 edges per iteration; interleaved butterfly reduce;
// deferred-max online softmax; fused residual+LN epilogue.
__global__ __launch_bounds__(256) void fused_node_kernel(
    const float* __restrict__ x, const __hip_bfloat16* __restrict__ xl_bf,
    const int* __restrict__ row_start, const int* __restrict__ cursor,
    const int* __restrict__ sorted_src, const float* __restrict__ sorted_ea,
    const float* __restrict__ We, const float* __restrict__ att,
    const float* __restrict__ bias, const float* __restrict__ rw_p,
    const float* __restrict__ gamma, const float* __restrict__ beta,
    float* __restrict__ out)
{
    const int v = blockIdx.x * 4 + (threadIdx.x >> 6);
    const int lane = threadIdx.x & 63;
    if (v >= N_NODES) return;
    const int begin = row_start[v];        // %4 == 0
    const int end   = cursor[v];           // begin + deg
    const size_t nb = (size_t)v * DIM + 2 * lane;
    const float2 xrv = *(const float2*)&out[nb];          // x_r row (parked)
    const float2 at  = *(const float2*)&att[2 * lane];
    const float2 we0 = *(const float2*)&We[0 * DIM + 2 * lane];
    const float2 we1 = *(const float2*)&We[1 * DIM + 2 * lane];
    const float2 we2 = *(const float2*)&We[2 * DIM + 2 * lane];

    float m = -3.4e38f, s = 0.f, a0 = 0.f, a1 = 0.f;
    int pos = begin;

    // ---- full batches of 4 (aligned int4/float4 loads) ----
    for (; pos + 4 <= end; pos += 4) {
        const int4 s4 = *(const int4*)(sorted_src + pos);
        const float4* eap = (const float4*)(sorted_ea + 3 * pos);
        const float4 eA = eap[0], eB = eap[1], eC = eap[2];
        // edge attrs: e0:(eA.x,eA.y,eA.z) e1:(eA.w,eB.x,eB.y) e2:(eB.z,eB.w,eC.x) e3:(eC.y,eC.z,eC.w)
        const unsigned xu0 = *(const unsigned*)&xl_bf[(size_t)s4.x * DIM + 2 * lane];
        const unsigned xu1 = *(const unsigned*)&xl_bf[(size_t)s4.y * DIM + 2 * lane];
        const unsigned xu2 = *(const unsigned*)&xl_bf[(size_t)s4.z * DIM + 2 * lane];
        const unsigned xu3 = *(const unsigned*)&xl_bf[(size_t)s4.w * DIM + 2 * lane];
        const float xl00 = __uint_as_float(xu0 << 16), xl10 = __uint_as_float(xu0 & 0xffff0000u);
        const float xl01 = __uint_as_float(xu1 << 16), xl11 = __uint_as_float(xu1 & 0xffff0000u);
        const float xl02 = __uint_as_float(xu2 << 16), xl12 = __uint_as_float(xu2 & 0xffff0000u);
        const float xl03 = __uint_as_float(xu3 << 16), xl13 = __uint_as_float(xu3 & 0xffff0000u);

        float P0, P1, P2, P3;
        {
            float t0, t1;
            t0 = xl00 + xrv.x + eA.x * we0.x + eA.y * we1.x + eA.z * we2.x;
            t1 = xl10 + xrv.y + eA.x * we0.y + eA.y * we1.y + eA.z * we2.y;
            t0 = t0 > 0.f ? t0 : NEG_SLOPE * t0;  t1 = t1 > 0.f ? t1 : NEG_SLOPE * t1;
            P0 = t0 * at.x + t1 * at.y;
            t0 = xl01 + xrv.x + eA.w * we0.x + eB.x * we1.x + eB.y * we2.x;
            t1 = xl11 + xrv.y + eA.w * we0.y + eB.x * we1.y + eB.y * we2.y;
            t0 = t0 > 0.f ? t0 : NEG_SLOPE * t0;  t1 = t1 > 0.f ? t1 : NEG_SLOPE * t1;
            P1 = t0 * at.x + t1 * at.y;
            t0 = xl02 + xrv.x + eB.z * we0.x + eB.w * we1.x + eC.x * we2.x;
            t1 = xl12 + xrv.y + eB.z * we0.y + eB.w * we1.y + eC.x * we2.y;
            t0 = t0 > 0.f ? t0 : NEG_SLOPE * t0;  t1 = t1 > 0.f ? t1 : NEG_SLOPE * t1;
            P2 = t0 * at.x + t1 * at.y;
            t0 = xl03 + xrv.x + eC.y * we0.x + eC.z * we1.x + eC.w * we2.x;
            t1 = xl13 + xrv.y + eC.y * we0.y + eC.z * we1.y + eC.w * we2.y;
            t0 = t0 > 0.f ? t0 : NEG_SLOPE * t0;  t1 = t1 > 0.f ? t1 : NEG_SLOPE * t1;
            P3 = t0 * at.x + t1 * at.y;
        }
        // interleaved butterfly: 14 shuffles for 4 sums
        const float tA0 = __shfl_xor(P0, 1, 64);
        const float tA1 = __shfl_xor(P1, 1, 64);
        const float tB0 = __shfl_xor(P2, 1, 64);
        const float tB1 = __shfl_xor(P3, 1, 64);
        const bool b0 = (lane & 1);
        float A = b0 ? (P1 + tA1) : (P0 + tA0);
        float B = b0 ? (P3 + tB1) : (P2 + tB0);
        const float tA = __shfl_xor(A, 2, 64);
        const float tB = __shfl_xor(B, 2, 64);
        float C = (lane & 2) ? (B + tB) : (A + tA);
        C += __shfl_xor(C, 4, 64);
        C += __shfl_xor(C, 8, 64);
        C += __shfl_xor(C, 16, 64);
        C += __shfl_xor(C, 32, 64);           // C(l) = S_{l&3}
        const int base = lane & ~3;
        const float p0 = __shfl(C, base + 0, 64);
        const float p1 = __shfl(C, base + 1, 64);
        const float p2 = __shfl(C, base + 2, 64);
        const float p3 = __shfl(C, base + 3, 64);

        const float pm = fmaxf(fmaxf(p0, p1), fmaxf(p2, p3));
        if (pm <= m + 8.f) {                  // defer-max fast path (wave-uniform)
            const float w0 = __expf(p0 - m), w1 = __expf(p1 - m);
            const float w2 = __expf(p2 - m), w3 = __expf(p3 - m);
            s  += (w0 + w1) + (w2 + w3);
            a0 += w0 * xl00 + w1 * xl01 + w2 * xl02 + w3 * xl03;
            a1 += w0 * xl10 + w1 * xl11 + w2 * xl12 + w3 * xl13;
        } else {
            const float mn = fmaxf(m, pm);
            const float f  = __expf(m - mn);
            const float w0 = __expf(p0 - mn), w1 = __expf(p1 - mn);
            const float w2 = __expf(p2 - mn), w3 = __expf(p3 - mn);
            s  = s  * f + (w0 + w1) + (w2 + w3);
            a0 = a0 * f + w0 * xl00 + w1 * xl01 + w2 * xl02 + w3 * xl03;
            a1 = a1 * f + w0 * xl10 + w1 * xl11 + w2 * xl12 + w3 * xl13;
            m = mn;
        }
    }

    // ---- tail (1-3 edges), scalar path ----
    for (; pos < end; ++pos) {
        const int sn = sorted_src[pos];
        const float ea0 = sorted_ea[3 * pos + 0];
        const float ea1 = sorted_ea[3 * pos + 1];
        const float ea2 = sorted_ea[3 * pos + 2];
        const unsigned xu = *(const unsigned*)&xl_bf[(size_t)sn * DIM + 2 * lane];
        const float xl0 = __uint_as_float(xu << 16);
        const float xl1 = __uint_as_float(xu & 0xffff0000u);
        float t0 = xl0 + xrv.x + ea0 * we0.x + ea1 * we1.x + ea2 * we2.x;
        float t1 = xl1 + xrv.y + ea0 * we0.y + ea1 * we1.y + ea2 * we2.y;
        t0 = t0 > 0.f ? t0 : NEG_SLOPE * t0;
        t1 = t1 > 0.f ? t1 : NEG_SLOPE * t1;
        float p = t0 * at.x + t1 * at.y;
#pragma unroll
        for (int o = 32; o > 0; o >>= 1) p += __shfl_xor(p, o, 64);
        if (p <= m + 8.f) {
            const float w = __expf(p - m);
            s += w; a0 += w * xl0; a1 += w * xl1;
        } else {
            const float mn = fmaxf(m, p);
            const float f = __expf(m - mn);
            const float w = __expf(p - mn);
            s = s * f + w; a0 = a0 * f + w * xl0; a1 = a1 * f + w * xl1;
            m = mn;
        }
    }

    const float inv = 1.f / (s + 1e-16f);

    // epilogue: residual + LayerNorm
    const float2 xv = *(const float2*)&x[nb];
    const float rw = rw_p[0];
    float v0 = xv.x + rw * (a0 * inv + bias[2 * lane]);
    float v1 = xv.y + rw * (a1 * inv + bias[2 * lane + 1]);
    float sum = v0 + v1;
#pragma unroll
    for (int o = 32; o > 0; o >>= 1) sum += __shfl_xor(sum, o, 64);
    const float mu = sum * (1.f / DIM);
    const float d0 = v0 - mu, d1 = v1 - mu;
    float q = d0 * d0 + d1 * d1;
#pragma unroll
    for (int o = 32; o > 0; o >>= 1) q += __shfl_xor(q, o, 64);
    const float rstd = rsqrtf(q * (1.f / DIM) + LN_EPS);
    float2 r;
    r.x = d0 * rstd * gamma[2 * lane]     + beta[2 * lane];
    r.y = d1 * rstd * gamma[2 * lane + 1] + beta[2 * lane + 1];
    *(float2*)&out[nb] = r;
}

extern "C" void kernel_launch(void* const* d_in, const int* in_sizes, int n_in,
                              void* d_out, int out_size, void* d_ws, size_t ws_size,
                              hipStream_t stream)
{
    const float* x    = (const float*)d_in[0];
    const int*   ei   = (const int*)d_in[1];
    const float* ea   = (const float*)d_in[2];
    const float* Wl   = (const float*)d_in[3];
    const float* bl   = (const float*)d_in[4];
    const float* Wr   = (const float*)d_in[5];
    const float* br   = (const float*)d_in[6];
    const float* We   = (const float*)d_in[7];
    const float* att  = (const float*)d_in[8];
    const float* bias = (const float*)d_in[9];
    const float* rw   = (const float*)d_in[10];
    const float* gmm  = (const float*)d_in[11];
    const float* bta  = (const float*)d_in[12];
    float* out = (float*)d_out;

    const int* src_idx = ei;            // edge_index[0]
    const int* dst_idx = ei + N_EDGES;  // edge_index[1]

    __hip_bfloat16* xl_bf = (__hip_bfloat16*)d_ws;                 // N*D bf16
    int*   sorted_src = (int*)(xl_bf + (size_t)N_NODES * DIM);     // PADCAP
    float* sorted_ea  = (float*)(sorted_src + PADCAP);             // 3*PADCAP
    int*   row_start  = (int*)(sorted_ea + (size_t)3 * PADCAP);    // N
    int*   cursor     = row_start + N_NODES;                       // N
    int*   partials   = cursor + N_NODES;                          // 256

    hipMemsetAsync(row_start, 0, (size_t)N_NODES * sizeof(int), stream);
    hist_kernel<<<(N_EDGES + 255) / 256, 256, 0, stream>>>(dst_idx, row_start);
    scan1_kernel<<<NB_SCAN, SCAN_BS, 0, stream>>>(row_start, partials);
    scan2_kernel<<<1, SCAN_BS, 0, stream>>>(partials);
    scan3_kernel<<<NB_SCAN, SCAN_BS, 0, stream>>>(row_start, partials, cursor);
    scatter_kernel<<<(N_EDGES + 255) / 256, 256, 0, stream>>>(src_idx, dst_idx, ea,
                                                              cursor, sorted_src, sorted_ea);
    lin_kernel<<<(N_NODES + 7) / 8, 256, 0, stream>>>(x, Wl, bl, Wr, br, xl_bf, out);
    fused_node_kernel<<<(N_NODES + 3) / 4, 256, 0, stream>>>(x, xl_bf, row_start, cursor,
                                                             sorted_src, sorted_ea,
                                                             We, att, bias, rw, gmm, bta, out);
}